// Round 1
// baseline (521.369 us; speedup 1.0000x reference)
//
#include <hip/hip_runtime.h>
#include <hip/hip_bf16.h>
#include <stdint.h>

// out = x @ (sum_e w1[e] @ w2[e])   -- reassociated two-einsum.
// GEMM1: W[h][h2] += w1[e][h][:] . w2t[e][h2][:]   (split-K over e, fp32 atomics)
// GEMM2: out = x @ W (via Wt bf16)

#define BM 128
#define BN 128
#define BK 32

typedef __attribute__((ext_vector_type(8))) short short8;
typedef __attribute__((ext_vector_type(4))) float float4v;
typedef __attribute__((ext_vector_type(4))) unsigned int uint4v;

__device__ __forceinline__ unsigned int rne_hi(unsigned int u) {
  // top 16 bits become RNE bf16 of the float with bits u
  return u + 0x7fffu + ((u >> 16) & 1u);
}

__device__ __forceinline__ unsigned int pack_bf16(float lo, float hi) {
  unsigned int ulo = rne_hi(__float_as_uint(lo));
  unsigned int uhi = rne_hi(__float_as_uint(hi));
  // dst = [uhi.b3 uhi.b2 ulo.b3 ulo.b2]  -> low ushort = bf16(lo)
  return __builtin_amdgcn_perm(uhi, ulo, 0x07060302u);
}

__device__ __forceinline__ void load_lds_16B(const void* g, void* lds) {
  // global -> LDS direct (dwordx4). LDS dest is wave-uniform base + lane*16.
  __builtin_amdgcn_global_load_lds(
      (__attribute__((address_space(1))) void*)(uintptr_t)g,
      (__attribute__((address_space(3))) void*)(unsigned int)(uintptr_t)lds,
      16, 0, 0);
}

// C[M][N](fp32) (+)= A(fp32,[m][k],lda) * Bt(bf16,[n][k],ldb)^T
// grid: (N/BN, M/BM, nsplit); z adds strideA/strideB; ATOMIC picks atomicAdd vs store.
template <bool ATOMIC>
__global__ __launch_bounds__(256) void gemm_f32a_bf16bt(
    const float* __restrict__ A, int lda, long strideA,
    const unsigned short* __restrict__ Bt, int ldb, long strideB,
    float* __restrict__ C, int ldc, int K) {
  __shared__ unsigned short As[BM * BK];  // [m][k], 64B rows
  __shared__ unsigned short Bs[BN * BK];  // [n][k], 64B rows

  const int tid = threadIdx.x;
  const int wv = tid >> 6;
  const int ln = tid & 63;
  const int wm = (wv >> 1) * 64;  // wave row offset in tile
  const int wn = (wv & 1) * 64;   // wave col offset in tile
  const int lrow = ln & 15;
  const int lq = ln >> 4;

  const float* Ab = A + (long)blockIdx.z * strideA + (long)(blockIdx.y * BM) * lda;
  const unsigned short* Bb = Bt + (long)blockIdx.z * strideB + (long)(blockIdx.x * BN) * ldb;

  float4v zero4 = {0.0f, 0.0f, 0.0f, 0.0f};
  float4v acc[4][4];
#pragma unroll
  for (int i = 0; i < 4; ++i)
#pragma unroll
    for (int j = 0; j < 4; ++j) acc[i][j] = zero4;

  const int nk = K / BK;
  for (int kt = 0; kt < nk; ++kt) {
    const int k0 = kt * BK;
    __syncthreads();  // WAR: prev iter's frag reads done before restage
    // ---- stage A: fp32 global -> cvt bf16 -> ds_write_b128 ----
#pragma unroll
    for (int p = 0; p < 2; ++p) {
      int o = p * 256 + tid;       // oct index: 512 octs of 8 elems
      int r = o >> 2;              // row 0..127
      int c8 = (o & 3) * 8;        // k-offset 0/8/16/24
      const float* g = Ab + (long)r * lda + k0 + c8;
      float4 v0 = *(const float4*)g;
      float4 v1 = *(const float4*)(g + 4);
      uint4v d;
      d.x = pack_bf16(v0.x, v0.y);
      d.y = pack_bf16(v0.z, v0.w);
      d.z = pack_bf16(v1.x, v1.y);
      d.w = pack_bf16(v1.z, v1.w);
      *(uint4v*)((char*)As + o * 16) = d;
    }
    // ---- stage B: bf16 global -> LDS direct ----
#pragma unroll
    for (int p = 0; p < 2; ++p) {
      int o = p * 256 + wv * 64 + ln;
      int r = o >> 2;
      int c8 = (o & 3) * 8;
      const unsigned short* g = Bb + (long)r * ldb + k0 + c8;
      char* lp = (char*)Bs + (p * 256 + wv * 64) * 16;  // wave-uniform base
      load_lds_16B(g, lp);
    }
    __syncthreads();  // RAW: staging (vmcnt+lgkmcnt) drained

    short8 a[4], b[4];
#pragma unroll
    for (int i = 0; i < 4; ++i)
      a[i] = *(const short8*)((const char*)As + (wm + i * 16 + lrow) * 64 + lq * 16);
#pragma unroll
    for (int j = 0; j < 4; ++j)
      b[j] = *(const short8*)((const char*)Bs + (wn + j * 16 + lrow) * 64 + lq * 16);
#pragma unroll
    for (int i = 0; i < 4; ++i)
#pragma unroll
      for (int j = 0; j < 4; ++j)
        acc[i][j] = __builtin_amdgcn_mfma_f32_16x16x32_bf16(a[i], b[j], acc[i][j], 0, 0, 0);
  }

  // epilogue: C/D layout col=lane&15, row=(lane>>4)*4+reg
  const int crow0 = blockIdx.y * BM + wm + lq * 4;
  const int ccol0 = blockIdx.x * BN + wn + lrow;
#pragma unroll
  for (int i = 0; i < 4; ++i)
#pragma unroll
    for (int j = 0; j < 4; ++j)
#pragma unroll
      for (int r = 0; r < 4; ++r) {
        int row = crow0 + i * 16 + r;
        int col = ccol0 + j * 16;
        if (ATOMIC)
          atomicAdd(&C[(long)row * ldc + col], acc[i][j][r]);
        else
          C[(long)row * ldc + col] = acc[i][j][r];
      }
}

// in: fp32 [z][R][C]  ->  out: bf16 [z][C][R]   (64x64 LDS tile transpose + cvt)
__global__ __launch_bounds__(256) void transpose_cvt_kernel(
    const float* __restrict__ in, unsigned short* __restrict__ out,
    int R, int C, long strideBatch) {
  __shared__ float tile[64][65];
  const float* src = in + (long)blockIdx.z * strideBatch;
  unsigned short* dst = out + (long)blockIdx.z * strideBatch;
  const int t = threadIdx.x;
  const int c4 = (t & 15) * 4;
  const int r0 = t >> 4;
  const int by = blockIdx.y * 64;  // R offset
  const int bx = blockIdx.x * 64;  // C offset
#pragma unroll
  for (int p = 0; p < 4; ++p) {
    int r = r0 + p * 16;
    float4 v = *(const float4*)(src + (long)(by + r) * C + bx + c4);
    tile[r][c4 + 0] = v.x;
    tile[r][c4 + 1] = v.y;
    tile[r][c4 + 2] = v.z;
    tile[r][c4 + 3] = v.w;
  }
  __syncthreads();
#pragma unroll
  for (int p = 0; p < 4; ++p) {
    int cc = r0 + p * 16;  // out-row (C dim) within tile
    int rr = c4;           // out-col (R dim) within tile
    unsigned int d0 = pack_bf16(tile[rr + 0][cc], tile[rr + 1][cc]);
    unsigned int d1 = pack_bf16(tile[rr + 2][cc], tile[rr + 3][cc]);
    uint2 dd;
    dd.x = d0;
    dd.y = d1;
    *(uint2*)(dst + (long)(bx + cc) * R + by + rr) = dd;
  }
}

extern "C" void kernel_launch(void* const* d_in, const int* in_sizes, int n_in,
                              void* d_out, int out_size, void* d_ws, size_t ws_size,
                              hipStream_t stream) {
  const float* x = (const float*)d_in[0];   // [4,1024,1024]
  const float* w1 = (const float*)d_in[1];  // [8,1024,4096]
  const float* w2 = (const float*)d_in[2];  // [8,4096,1024]
  float* out = (float*)d_out;               // [4,1024,1024]

  const int A_ = 4, M_ = 1024, H_ = 1024, E_ = 8, N_ = 4096;

  // ws layout: w2t bf16 (67.1MB) | Wacc f32 (4.2MB) | Wt bf16 (2.1MB)
  unsigned short* w2t = (unsigned short*)d_ws;
  float* Wacc = (float*)((char*)d_ws + (size_t)E_ * H_ * N_ * 2);
  unsigned short* Wt = (unsigned short*)((char*)Wacc + (size_t)H_ * H_ * 4);

  // 1) w2 [E][N][H] -> w2t [E][H][N] (bf16)
  transpose_cvt_kernel<<<dim3(H_ / 64, N_ / 64, E_), 256, 0, stream>>>(
      w2, w2t, N_, H_, (long)N_ * H_);

  // 2) zero the W accumulator
  hipMemsetAsync(Wacc, 0, (size_t)H_ * H_ * 4, stream);

  // 3) GEMM1: W += w1[e] @ w2[e]  (split-K over e, atomic fp32 epilogue)
  gemm_f32a_bf16bt<true><<<dim3(H_ / BN, H_ / BM, E_), 256, 0, stream>>>(
      w1, N_, (long)H_ * N_, w2t, N_, (long)H_ * N_, Wacc, H_, N_);

  // 4) W f32 [H][H] -> Wt bf16 [H][H]^T
  transpose_cvt_kernel<<<dim3(H_ / 64, H_ / 64, 1), 256, 0, stream>>>(
      Wacc, Wt, H_, H_, 0);

  // 5) GEMM2: out = x @ W
  gemm_f32a_bf16bt<false><<<dim3(H_ / BN, (A_ * M_) / BM, 1), 256, 0, stream>>>(
      x, H_, 0, Wt, H_, 0, out, H_, H_);
}